// Round 1
// baseline (2790.229 us; speedup 1.0000x reference)
//
#include <hip/hip_runtime.h>

// SparseConv3d rulebook scatter-GEMM, MI355X (gfx950)
// out[oi] += x[ii] @ W[k]  for 27M rules; then + bias (folded into init).

#define K3    27
#define RULES 1000000
#define CIN   32
#define COUT  32
#define NOUT  2000000

// ---------------- Kernel A: out[r][c] = bias[c] ----------------
__global__ __launch_bounds__(256) void bias_init_kernel(
    float* __restrict__ out, const float* __restrict__ bias) {
  float4 b[8];
#pragma unroll
  for (int j = 0; j < 8; ++j)
    b[j] = reinterpret_cast<const float4*>(bias)[j];
  const size_t total4 = (size_t)NOUT * COUT / 4;  // 16M float4
  const size_t stride = (size_t)gridDim.x * blockDim.x;
  for (size_t i = (size_t)blockIdx.x * blockDim.x + threadIdx.x; i < total4;
       i += stride) {
    reinterpret_cast<float4*>(out)[i] = b[i & 7];
  }
}

// ---------------- Kernel B: per-rule gather * W[k] -> coalesced atomic scatter ----------------
__global__ __launch_bounds__(256) void scatter_gemm_kernel(
    const float* __restrict__ x, const float* __restrict__ weights,
    const int* __restrict__ in_inds, const int* __restrict__ out_inds,
    float* __restrict__ out) {
  const int k    = blockIdx.y;              // wave-uniform -> W loads scalarize
  const int e    = blockIdx.x * 256 + threadIdx.x;
  const int wave = threadIdx.x >> 6;
  const int lane = threadIdx.x & 63;

  __shared__ float sacc[4][64][33];  // +1 pad: conflict-free write & read
  __shared__ int   soi[4][64];

  const bool valid = (e < RULES);
  int ii = 0, oi = -1;
  if (valid) {
    ii = in_inds[(size_t)k * RULES + e];
    oi = out_inds[(size_t)k * RULES + e];
  }

  // gather x row (32 floats = 8 x float4)
  float xr[CIN];
  if (valid) {
    const float4* __restrict__ xrow =
        reinterpret_cast<const float4*>(x + (size_t)ii * CIN);
#pragma unroll
    for (int j = 0; j < 8; ++j) {
      float4 v = xrow[j];
      xr[4 * j + 0] = v.x;
      xr[4 * j + 1] = v.y;
      xr[4 * j + 2] = v.z;
      xr[4 * j + 3] = v.w;
    }
  } else {
#pragma unroll
    for (int j = 0; j < CIN; ++j) xr[j] = 0.f;
  }

  // acc[c] = sum_i xr[i] * W[k][i][c] ; W addresses are lane-invariant -> s_load
  float acc[COUT];
#pragma unroll
  for (int c = 0; c < COUT; ++c) acc[c] = 0.f;

  const float* __restrict__ wk = weights + (size_t)k * CIN * COUT;
#pragma unroll
  for (int i = 0; i < CIN; ++i) {
    const float xi = xr[i];
#pragma unroll
    for (int c = 0; c < COUT; ++c) acc[c] += xi * wk[i * COUT + c];
  }

  // stage through LDS so atomics are 128B-contiguous per entry
#pragma unroll
  for (int c = 0; c < COUT; ++c) sacc[wave][lane][c] = acc[c];
  if (lane < 64) soi[wave][lane] = oi;
  __syncthreads();

  // 64 lanes cover 2 entries x 32 channels per iteration
  const int half = lane >> 5;   // 0/1
  const int c    = lane & 31;
#pragma unroll
  for (int it = 0; it < 32; ++it) {
    const int eidx = it * 2 + half;
    const int o    = soi[wave][eidx];
    if (o >= 0) {
      atomicAdd(&out[(size_t)o * COUT + c], sacc[wave][eidx][c]);
    }
  }
}

extern "C" void kernel_launch(void* const* d_in, const int* in_sizes, int n_in,
                              void* d_out, int out_size, void* d_ws,
                              size_t ws_size, hipStream_t stream) {
  const float* x       = (const float*)d_in[0];
  const float* weights = (const float*)d_in[1];
  const float* bias    = (const float*)d_in[2];
  const int*   in_inds = (const int*)d_in[3];
  const int*   out_inds= (const int*)d_in[4];
  float*       out     = (float*)d_out;

  bias_init_kernel<<<2048, 256, 0, stream>>>(out, bias);

  dim3 grid((RULES + 255) / 256, K3);
  scatter_gemm_kernel<<<grid, 256, 0, stream>>>(x, weights, in_inds, out_inds,
                                                out);
}